// Round 1
// baseline (584.226 us; speedup 1.0000x reference)
//
#include <hip/hip_runtime.h>

// BitNetAttention on MI355X (gfx950).
// Core trick: activation_quant => activations are n*(max/127), n integer in [-127,127];
// weight_quant => weights are sgn*scale_w, sgn in {-1,0,1}. Both exact in bf16, so
// bf16 MFMA with fp32 accumulation computes the bitlinear matmuls EXACTLY
// (integer sums bounded by 2048*127 < 2^24). Scales applied in fp32 epilogue.

#define DI __device__ __forceinline__

using bf16   = __bf16;
using bf16x8 = __attribute__((ext_vector_type(8))) __bf16;
using f32x4  = __attribute__((ext_vector_type(4))) float;

constexpr int S_LEN = 2048;
constexpr int HDIM  = 2048;
constexpr int NH    = 16;
constexpr int NKV   = 8;
constexpr int HD    = 128;
constexpr int BATCH = 2;
constexpr int M_TOK = BATCH * S_LEN; // 4096

DI void gl_lds16(void* lds, const void* g) {
  __builtin_amdgcn_global_load_lds((const __attribute__((address_space(1))) void*)g,
                                   (__attribute__((address_space(3))) void*)lds, 16, 0, 0);
}
DI float clampf(float x, float lo, float hi) { return fminf(fmaxf(x, lo), hi); }

DI float block_sum(float v, float* red, int lane, int w) {
#pragma unroll
  for (int o = 32; o > 0; o >>= 1) v += __shfl_xor(v, o, 64);
  __syncthreads();
  if (lane == 0) red[w] = v;
  __syncthreads();
  return red[0] + red[1] + red[2] + red[3];
}
DI float block_max(float v, float* red, int lane, int w) {
#pragma unroll
  for (int o = 32; o > 0; o >>= 1) v = fmaxf(v, __shfl_xor(v, o, 64));
  __syncthreads();
  if (lane == 0) red[w] = v;
  __syncthreads();
  return fmaxf(fmaxf(red[0], red[1]), fmaxf(red[2], red[3]));
}

// ---------------- weight stats: mean and mean|w| per matrix ----------------
__global__ void wstats_kernel(const float* wq, const float* wk, const float* wv,
                              const float* wo, float* stats) {
  __shared__ float red[4], red2[4];
  int t = threadIdx.x, lane = t & 63, w = t >> 6;
  int m = blockIdx.y;
  const float* src; int n4;
  if (m == 0)      { src = wq; n4 = 1048576; }
  else if (m == 1) { src = wk; n4 = 524288;  }
  else if (m == 2) { src = wv; n4 = 524288;  }
  else             { src = wo; n4 = 1048576; }
  float s = 0.f, sa = 0.f;
  for (int i = blockIdx.x * 256 + t; i < n4; i += 256 * 256) {
    float4 v = ((const float4*)src)[i];
    s  += v.x + v.y + v.z + v.w;
    sa += fabsf(v.x) + fabsf(v.y) + fabsf(v.z) + fabsf(v.w);
  }
#pragma unroll
  for (int o = 32; o > 0; o >>= 1) { s += __shfl_xor(s, o, 64); sa += __shfl_xor(sa, o, 64); }
  if (lane == 0) { red[w] = s; red2[w] = sa; }
  __syncthreads();
  if (t == 0) {
    atomicAdd(&stats[2 * m],     red[0] + red[1] + red[2] + red[3]);
    atomicAdd(&stats[2 * m + 1], red2[0] + red2[1] + red2[2] + red2[3]);
  }
}

// ---------------- ternary sign quant: sign(w - mean) as bf16 ±1 ----------------
__global__ void wsign_kernel(const float* wq, const float* wk, const float* wv, const float* wo,
                             ushort* sq, ushort* sk, ushort* sv, ushort* so,
                             const float* stats) {
  int m = blockIdx.y;
  const float* src; ushort* dst; int n4; float cinv;
  if (m == 0)      { src = wq; dst = sq; n4 = 1048576; cinv = 1.f / 4194304.f; }
  else if (m == 1) { src = wk; dst = sk; n4 = 524288;  cinv = 1.f / 2097152.f; }
  else if (m == 2) { src = wv; dst = sv; n4 = 524288;  cinv = 1.f / 2097152.f; }
  else             { src = wo; dst = so; n4 = 1048576; cinv = 1.f / 4194304.f; }
  float e = stats[2 * m] * cinv;
  for (int i = blockIdx.x * 256 + threadIdx.x; i < n4; i += 1024 * 256) {
    float4 v = ((const float4*)src)[i];
    ushort4 o;
    o.x = v.x > e ? 0x3F80 : (v.x < e ? 0xBF80 : 0);
    o.y = v.y > e ? 0x3F80 : (v.y < e ? 0xBF80 : 0);
    o.z = v.z > e ? 0x3F80 : (v.z < e ? 0xBF80 : 0);
    o.w = v.w > e ? 0x3F80 : (v.w < e ? 0xBF80 : 0);
    ((ushort4*)dst)[i] = o;
  }
}

// ---------------- RoPE tables ----------------
__global__ void ropetab_kernel(float* ct, float* st) {
  int s = blockIdx.x, j = threadIdx.x; // 2048 x 64
  float invf = powf(10000.f, -(float)j * (1.f / 64.f));
  float a = (float)s * invf;
  ct[s * 64 + j] = cosf(a);
  st[s * 64 + j] = sinf(a);
}

// ---------------- fused RMSNorm + activation quant (1 or 3 norm weights) ----------------
DI void quant_one(const float* xs, const float* __restrict__ wt, bf16* __restrict__ a,
                  float* __restrict__ r, int row, int t, int lane, int w, float* red) {
  float4 w0 = ((const float4*)wt)[t * 2], w1 = ((const float4*)wt)[t * 2 + 1];
  float wv[8] = {w0.x, w0.y, w0.z, w0.w, w1.x, w1.y, w1.z, w1.w};
  float y[8]; float am = 0.f;
#pragma unroll
  for (int e = 0; e < 8; ++e) {
    y[e] = clampf(wv[e] * xs[e], -50.f, 50.f);
    am = fmaxf(am, fabsf(y[e]));
  }
  float mx = block_max(am, red, lane, w);
  float maxval = fmaxf(mx, 1e-4f);
  float sc = 127.f / maxval;
  bf16x8 q;
#pragma unroll
  for (int e = 0; e < 8; ++e) {
    float n = rintf(y[e] * sc);       // round-half-even, matches numpy
    n = clampf(n, -128.f, 127.f);
    q[e] = (bf16)n;                   // exact (small integer)
  }
  *(bf16x8*)(a + (size_t)row * 2048 + t * 8) = q;
  if (t == 0) r[row] = maxval * (1.f / 127.f);
}

template <int NW>
__launch_bounds__(256)
__global__ void rqnorm_kernel(const float* __restrict__ x,
                              const float* __restrict__ w0, const float* __restrict__ w1,
                              const float* __restrict__ w2,
                              bf16* a0, bf16* a1, bf16* a2,
                              float* r0, float* r1, float* r2) {
  __shared__ float red[4];
  int t = threadIdx.x, lane = t & 63, w = t >> 6;
  int row = blockIdx.x;
  const float* xr = x + (size_t)row * 2048;
  float4 u0 = ((const float4*)xr)[t * 2], u1 = ((const float4*)xr)[t * 2 + 1];
  float xs[8] = {u0.x, u0.y, u0.z, u0.w, u1.x, u1.y, u1.z, u1.w};
  float ss = 0.f;
#pragma unroll
  for (int e = 0; e < 8; ++e) { xs[e] = clampf(xs[e], -100.f, 100.f); ss += xs[e] * xs[e]; }
  float tot = block_sum(ss, red, lane, w);
  float var = fmaxf(tot * (1.f / 2048.f), 1e-5f);
  float inv = 1.f / sqrtf(var + 1e-5f);
#pragma unroll
  for (int e = 0; e < 8; ++e) xs[e] = clampf(xs[e] * inv, -10.f, 10.f);
  quant_one(xs, w0, a0, r0, row, t, lane, w, red);
  if (NW > 1) quant_one(xs, w1, a1, r1, row, t, lane, w, red);
  if (NW > 2) quant_one(xs, w2, a2, r2, row, t, lane, w, red);
}

// ---------------- bf16 MFMA GEMM: C = A * B^T, integer-exact, scaled epilogue ----------------
// A: [M_TOK x 2048] bf16 (integer n values); Bw: [N x 2048] bf16 signs.
// ROPE=1: epilogue applies RoPE and writes bf16 [b, h, s, d]; else fp32 row-major [M_TOK x N].
template <int N, int ROPE>
__launch_bounds__(256, 2)
__global__ void gemm_bt(const bf16* __restrict__ A, const bf16* __restrict__ Bw,
                        const float* __restrict__ rs, const float* __restrict__ stats,
                        int sidx, float cinv,
                        float* __restrict__ outf, bf16* __restrict__ outb, int nh,
                        const float* __restrict__ ct, const float* __restrict__ st) {
  __shared__ bf16 As[128 * 64];
  __shared__ bf16 Bs[128 * 64];
  int t = threadIdx.x, w = t >> 6, lane = t & 63;
  int l15 = lane & 15, quad = lane >> 4;
  int m0 = blockIdx.y * 128, n0 = blockIdx.x * 128;
  f32x4 acc[2][8] = {};
  int srow = w * 8 + (lane >> 3);
  int scol = (lane & 7) * 8;
  const bf16* Ag = A + (size_t)(m0 + srow) * 2048 + scol;
  const bf16* Bg = Bw + (size_t)(n0 + srow) * 2048 + scol;
  bf16* Al = As + srow * 64 + scol;
  bf16* Bl = Bs + srow * 64 + scol;
  for (int kt = 0; kt < 32; ++kt) {
    size_t kb = (size_t)kt * 64;
#pragma unroll
    for (int i = 0; i < 4; ++i) {
      gl_lds16(Al + i * 32 * 64, Ag + (size_t)i * 32 * 2048 + kb);
      gl_lds16(Bl + i * 32 * 64, Bg + (size_t)i * 32 * 2048 + kb);
    }
    __syncthreads();
#pragma unroll
    for (int kc = 0; kc < 2; ++kc) {
      bf16x8 af[2], bfr[8];
#pragma unroll
      for (int mt = 0; mt < 2; ++mt)
        af[mt] = *(const bf16x8*)(As + (w * 32 + mt * 16 + l15) * 64 + kc * 32 + quad * 8);
#pragma unroll
      for (int nt = 0; nt < 8; ++nt)
        bfr[nt] = *(const bf16x8*)(Bs + (nt * 16 + l15) * 64 + kc * 32 + quad * 8);
#pragma unroll
      for (int mt = 0; mt < 2; ++mt)
#pragma unroll
        for (int nt = 0; nt < 8; ++nt)
          acc[mt][nt] = __builtin_amdgcn_mfma_f32_16x16x32_bf16(af[mt], bfr[nt], acc[mt][nt], 0, 0, 0);
    }
    __syncthreads();
  }
  float sw = fmaxf(stats[sidx] * cinv, 1e-8f);
#pragma unroll
  for (int mt = 0; mt < 2; ++mt) {
#pragma unroll
    for (int r = 0; r < 4; ++r) {
      int row = m0 + w * 32 + mt * 16 + quad * 4 + r;
      float rsv = rs[row] * sw;
      if (ROPE) {
        int s = row & 2047, b = row >> 11, h = blockIdx.x;
        size_t base = ((size_t)(b * nh + h) * 2048 + s) * 128;
#pragma unroll
        for (int nt = 0; nt < 4; ++nt) {
          int d = nt * 16 + l15;
          float x1 = acc[mt][nt][r] * rsv;
          float x2 = acc[mt][nt + 4][r] * rsv;
          float c = ct[s * 64 + d], sn = st[s * 64 + d];
          outb[base + d]      = (bf16)(x1 * c - x2 * sn);
          outb[base + d + 64] = (bf16)(x2 * c + x1 * sn);
        }
      } else {
#pragma unroll
        for (int nt = 0; nt < 8; ++nt)
          outf[(size_t)row * N + n0 + nt * 16 + l15] = acc[mt][nt][r] * rsv;
      }
    }
  }
}

// ---------------- V transpose: [token, 1024] fp32 -> bf16 [b, kvh, d, s] ----------------
__global__ void vtrans_kernel(const float* __restrict__ v_lin, bf16* __restrict__ v_t) {
  __shared__ float tile[64][65];
  int t = threadIdx.x, c = t & 63, rq = t >> 6;
  int ct0 = blockIdx.x * 64, tt0 = blockIdx.y * 64;
#pragma unroll
  for (int i = 0; i < 16; ++i) {
    int r = rq * 16 + i;
    tile[r][c] = v_lin[(size_t)(tt0 + r) * 1024 + ct0 + c];
  }
  __syncthreads();
  int token = tt0 + c;
  int b = token >> 11, s = token & 2047;
#pragma unroll
  for (int i = 0; i < 16; ++i) {
    int cg = ct0 + rq * 16 + i;
    int kvh = cg >> 7, d = cg & 127;
    v_t[((size_t)(b * 8 + kvh) * 128 + d) * 2048 + s] = (bf16)tile[c][rq * 16 + i];
  }
}

// ---------------- flash attention: q-tile 128, k-tile 64, online softmax ----------------
__launch_bounds__(256, 2)
__global__ void attn_kernel(const bf16* __restrict__ Q, const bf16* __restrict__ Kc,
                            const bf16* __restrict__ Vt, const float* __restrict__ mask,
                            float* __restrict__ Oout) {
  constexpr float scale = 0.08838834764831845f; // 1/sqrt(128)
  __shared__ bf16 Ks[64 * 128];  // [kk][d]
  __shared__ bf16 Vs[128 * 64];  // [d][kk]
  __shared__ bf16 Ps[128 * 64];  // [q][kk]
  int t = threadIdx.x, w = t >> 6, lane = t & 63;
  int l15 = lane & 15, quad = lane >> 4;
  int bh = blockIdx.y, b = bh >> 4, h = bh & 15, kvh = h >> 1;
  int q0 = blockIdx.x * 128;
  const bf16* Qb = Q + (size_t)(b * 16 + h) * 2048 * 128;
  const bf16* Kb = Kc + (size_t)(b * 8 + kvh) * 2048 * 128;
  const bf16* Vb = Vt + (size_t)(b * 8 + kvh) * 128 * 2048;

  bf16x8 qf[2][4];
  int qw = q0 + w * 32;
#pragma unroll
  for (int mt = 0; mt < 2; ++mt)
#pragma unroll
    for (int kc = 0; kc < 4; ++kc)
      qf[mt][kc] = *(const bf16x8*)(Qb + (size_t)(qw + mt * 16 + l15) * 128 + kc * 32 + quad * 8);

  f32x4 Oa[2][8] = {};
  float mrow[2][4], lrow[2][4];
#pragma unroll
  for (int mt = 0; mt < 2; ++mt)
#pragma unroll
    for (int r = 0; r < 4; ++r) { mrow[mt][r] = -1e30f; lrow[mt][r] = 0.f; }

  int krow = w * 4 + quad, kcol = l15 * 8;       // K staging
  int vrow = w * 8 + (lane >> 3), vcol = (lane & 7) * 8; // V staging

  for (int kt = 0; kt < 32; ++kt) {
    int kk0 = kt * 64;
#pragma unroll
    for (int i = 0; i < 4; ++i) {
      gl_lds16(Ks + (i * 16 + krow) * 128 + kcol, Kb + (size_t)(kk0 + i * 16 + krow) * 128 + kcol);
      gl_lds16(Vs + (i * 32 + vrow) * 64 + vcol, Vb + (size_t)(i * 32 + vrow) * 2048 + kk0 + vcol);
    }
    __syncthreads();

    f32x4 Sacc[2][4];
#pragma unroll
    for (int mt = 0; mt < 2; ++mt)
#pragma unroll
      for (int nt = 0; nt < 4; ++nt) Sacc[mt][nt] = 0.f;
#pragma unroll
    for (int kc = 0; kc < 4; ++kc) {
      bf16x8 kf[4];
#pragma unroll
      for (int nt = 0; nt < 4; ++nt)
        kf[nt] = *(const bf16x8*)(Ks + (nt * 16 + l15) * 128 + kc * 32 + quad * 8);
#pragma unroll
      for (int mt = 0; mt < 2; ++mt)
#pragma unroll
        for (int nt = 0; nt < 4; ++nt)
          Sacc[mt][nt] = __builtin_amdgcn_mfma_f32_16x16x32_bf16(qf[mt][kc], kf[nt], Sacc[mt][nt], 0, 0, 0);
    }

#pragma unroll
    for (int mt = 0; mt < 2; ++mt) {
#pragma unroll
      for (int nt = 0; nt < 4; ++nt)
#pragma unroll
        for (int r = 0; r < 4; ++r) {
          int qg = q0 + w * 32 + mt * 16 + quad * 4 + r;
          Sacc[mt][nt][r] = Sacc[mt][nt][r] * scale +
                            mask[(size_t)qg * 2048 + kk0 + nt * 16 + l15];
        }
#pragma unroll
      for (int r = 0; r < 4; ++r) {
        float mx = fmaxf(fmaxf(Sacc[mt][0][r], Sacc[mt][1][r]),
                         fmaxf(Sacc[mt][2][r], Sacc[mt][3][r]));
        mx = fmaxf(mx, __shfl_xor(mx, 1, 16));
        mx = fmaxf(mx, __shfl_xor(mx, 2, 16));
        mx = fmaxf(mx, __shfl_xor(mx, 4, 16));
        mx = fmaxf(mx, __shfl_xor(mx, 8, 16));
        float mnew = fmaxf(mrow[mt][r], mx);
        float alpha = __expf(mrow[mt][r] - mnew);
        mrow[mt][r] = mnew;
        float rsum = 0.f;
#pragma unroll
        for (int nt = 0; nt < 4; ++nt) {
          float p = __expf(Sacc[mt][nt][r] - mnew);
          Sacc[mt][nt][r] = p;
          rsum += p;
        }
        rsum += __shfl_xor(rsum, 1, 16);
        rsum += __shfl_xor(rsum, 2, 16);
        rsum += __shfl_xor(rsum, 4, 16);
        rsum += __shfl_xor(rsum, 8, 16);
        lrow[mt][r] = lrow[mt][r] * alpha + rsum;
#pragma unroll
        for (int nt = 0; nt < 8; ++nt) Oa[mt][nt][r] *= alpha;
#pragma unroll
        for (int nt = 0; nt < 4; ++nt)
          Ps[(w * 32 + mt * 16 + quad * 4 + r) * 64 + nt * 16 + l15] = (bf16)Sacc[mt][nt][r];
      }
    }
    __syncthreads();

#pragma unroll
    for (int kc = 0; kc < 2; ++kc) {
      bf16x8 pf[2];
#pragma unroll
      for (int mt = 0; mt < 2; ++mt)
        pf[mt] = *(const bf16x8*)(Ps + (w * 32 + mt * 16 + l15) * 64 + kc * 32 + quad * 8);
#pragma unroll
      for (int nt = 0; nt < 8; ++nt) {
        bf16x8 vf = *(const bf16x8*)(Vs + (nt * 16 + l15) * 64 + kc * 32 + quad * 8);
#pragma unroll
        for (int mt = 0; mt < 2; ++mt)
          Oa[mt][nt] = __builtin_amdgcn_mfma_f32_16x16x32_bf16(pf[mt], vf, Oa[mt][nt], 0, 0, 0);
      }
    }
    __syncthreads();
  }

#pragma unroll
  for (int mt = 0; mt < 2; ++mt)
#pragma unroll
    for (int r = 0; r < 4; ++r) {
      float inv = 1.f / lrow[mt][r];
      int token = b * 2048 + q0 + w * 32 + mt * 16 + quad * 4 + r;
#pragma unroll
      for (int nt = 0; nt < 8; ++nt)
        Oout[(size_t)token * 2048 + h * 128 + nt * 16 + l15] = Oa[mt][nt][r] * inv;
    }
}

// ---------------- launch ----------------
extern "C" void kernel_launch(void* const* d_in, const int* in_sizes, int n_in,
                              void* d_out, int out_size, void* d_ws, size_t ws_size,
                              hipStream_t stream) {
  const float* hidden = (const float*)d_in[0];
  const float* mask   = (const float*)d_in[1];
  const float* wq = (const float*)d_in[2];
  const float* wk = (const float*)d_in[3];
  const float* wv = (const float*)d_in[4];
  const float* wo = (const float*)d_in[5];
  const float* nq = (const float*)d_in[6];
  const float* nk = (const float*)d_in[7];
  const float* nv = (const float*)d_in[8];
  const float* no = (const float*)d_in[9];
  float* out = (float*)d_out;
  char* ws = (char*)d_ws;

  // workspace layout (bytes), 256-aligned
  constexpr size_t O_STATS = 0;                         // 32 B
  constexpr size_t O_CT    = 256;                       // 2048*64*4 = 524288
  constexpr size_t O_ST    = O_CT + 524288;
  constexpr size_t O_SQ    = O_ST + 524288;             // 2048*2048*2
  constexpr size_t O_SK    = O_SQ + 8388608;            // 1024*2048*2
  constexpr size_t O_SV    = O_SK + 4194304;
  constexpr size_t O_SO    = O_SV + 4194304;            // 8388608
  constexpr size_t O_RSQ   = O_SO + 8388608;            // 4096*4
  constexpr size_t O_RSK   = O_RSQ + 16384;
  constexpr size_t O_RSV   = O_RSK + 16384;
  constexpr size_t O_RSO   = O_RSV + 16384;
  constexpr size_t O_AQQ   = O_RSO + 16384;             // 4096*2048*2 = 16777216
  constexpr size_t O_AQK   = O_AQQ + 16777216;
  constexpr size_t O_AQV   = O_AQK + 16777216;
  constexpr size_t O_QR    = O_AQV + 16777216;          // bf16 [2,16,2048,128] = 16777216
  constexpr size_t O_KR    = O_QR + 16777216;           // bf16 [2,8,2048,128]  = 8388608
  constexpr size_t O_VT    = O_KR + 8388608;            // bf16 [2,8,128,2048]  = 8388608
  // aliases (stream-ordered, lifetimes disjoint):
  constexpr size_t O_VLIN  = O_AQQ;                     // fp32 [4096,1024] = 16777216 (after gemm_q)
  constexpr size_t O_ATTN  = O_AQQ;                     // fp32 [4096,2048] = 33554432 (after vtrans)
  constexpr size_t O_AQO   = O_AQV;                     // bf16 [4096,2048] (after gemm_v)

  float* stats = (float*)(ws + O_STATS);
  float* ct = (float*)(ws + O_CT);
  float* st = (float*)(ws + O_ST);

  hipMemsetAsync(ws + O_STATS, 0, 256, stream);

  wstats_kernel<<<dim3(256, 4), 256, 0, stream>>>(wq, wk, wv, wo, stats);
  wsign_kernel<<<dim3(1024, 4), 256, 0, stream>>>(wq, wk, wv, wo,
      (ushort*)(ws + O_SQ), (ushort*)(ws + O_SK), (ushort*)(ws + O_SV), (ushort*)(ws + O_SO), stats);
  ropetab_kernel<<<dim3(2048), 64, 0, stream>>>(ct, st);

  rqnorm_kernel<3><<<dim3(4096), 256, 0, stream>>>(hidden, nq, nk, nv,
      (bf16*)(ws + O_AQQ), (bf16*)(ws + O_AQK), (bf16*)(ws + O_AQV),
      (float*)(ws + O_RSQ), (float*)(ws + O_RSK), (float*)(ws + O_RSV));

  // Q projection (+RoPE fused) -> bf16 [b,h,s,d]
  gemm_bt<2048, 1><<<dim3(16, 32), 256, 0, stream>>>(
      (const bf16*)(ws + O_AQQ), (const bf16*)(ws + O_SQ), (float*)(ws + O_RSQ),
      stats, 1, 1.f / 4194304.f, nullptr, (bf16*)(ws + O_QR), 16, ct, st);
  // K projection (+RoPE) -> bf16 [b,kvh,s,d]
  gemm_bt<1024, 1><<<dim3(8, 32), 256, 0, stream>>>(
      (const bf16*)(ws + O_AQK), (const bf16*)(ws + O_SK), (float*)(ws + O_RSK),
      stats, 3, 1.f / 2097152.f, nullptr, (bf16*)(ws + O_KR), 8, ct, st);
  // V projection -> fp32 [token,1024]
  gemm_bt<1024, 0><<<dim3(8, 32), 256, 0, stream>>>(
      (const bf16*)(ws + O_AQV), (const bf16*)(ws + O_SV), (float*)(ws + O_RSV),
      stats, 5, 1.f / 2097152.f, (float*)(ws + O_VLIN), nullptr, 0, ct, st);

  vtrans_kernel<<<dim3(16, 64), 256, 0, stream>>>((const float*)(ws + O_VLIN), (bf16*)(ws + O_VT));

  attn_kernel<<<dim3(16, 32), 256, 0, stream>>>(
      (const bf16*)(ws + O_QR), (const bf16*)(ws + O_KR), (const bf16*)(ws + O_VT),
      mask, (float*)(ws + O_ATTN));

  rqnorm_kernel<1><<<dim3(4096), 256, 0, stream>>>((const float*)(ws + O_ATTN), no, no, no,
      (bf16*)(ws + O_AQO), (bf16*)(ws + O_AQO), (bf16*)(ws + O_AQO),
      (float*)(ws + O_RSO), (float*)(ws + O_RSO), (float*)(ws + O_RSO));

  gemm_bt<2048, 0><<<dim3(16, 32), 256, 0, stream>>>(
      (const bf16*)(ws + O_AQO), (const bf16*)(ws + O_SO), (float*)(ws + O_RSO),
      stats, 7, 1.f / 4194304.f, out, nullptr, 0, ct, st);

  (void)in_sizes; (void)n_in; (void)out_size; (void)ws_size;
}

// Round 2
// 501.408 us; speedup vs baseline: 1.1652x; 1.1652x over previous
//
#include <hip/hip_runtime.h>

// BitNetAttention on MI355X (gfx950).
// Bitlinear matmuls are integer-exact in bf16 MFMA (activations = n*(max/127),
// weights = sign*scale; integer sums < 2^24 accumulate exactly in fp32).
// R1: XOR-swizzled LDS everywhere (conflicts were 38% of attn cycles),
// single-barrier double-buffered attention K-loop, fused QKV GEMM.

#define DI __device__ __forceinline__

using bf16   = __bf16;
using bf16x8 = __attribute__((ext_vector_type(8))) __bf16;
using f32x4  = __attribute__((ext_vector_type(4))) float;

DI void gl_lds16(void* lds, const void* g) {
  __builtin_amdgcn_global_load_lds((const __attribute__((address_space(1))) void*)g,
                                   (__attribute__((address_space(3))) void*)lds, 16, 0, 0);
}
DI float clampf(float x, float lo, float hi) { return fminf(fmaxf(x, lo), hi); }

DI float block_sum(float v, float* red, int lane, int w) {
#pragma unroll
  for (int o = 32; o > 0; o >>= 1) v += __shfl_xor(v, o, 64);
  __syncthreads();
  if (lane == 0) red[w] = v;
  __syncthreads();
  return red[0] + red[1] + red[2] + red[3];
}
DI float block_max(float v, float* red, int lane, int w) {
#pragma unroll
  for (int o = 32; o > 0; o >>= 1) v = fmaxf(v, __shfl_xor(v, o, 64));
  __syncthreads();
  if (lane == 0) red[w] = v;
  __syncthreads();
  return fmaxf(fmaxf(red[0], red[1]), fmaxf(red[2], red[3]));
}

// ---------------- weight stats ----------------
__global__ void wstats_kernel(const float* wq, const float* wk, const float* wv,
                              const float* wo, float* stats) {
  __shared__ float red[4], red2[4];
  int t = threadIdx.x, lane = t & 63, w = t >> 6;
  int m = blockIdx.y;
  const float* src; int n4;
  if (m == 0)      { src = wq; n4 = 1048576; }
  else if (m == 1) { src = wk; n4 = 524288;  }
  else if (m == 2) { src = wv; n4 = 524288;  }
  else             { src = wo; n4 = 1048576; }
  float s = 0.f, sa = 0.f;
  for (int i = blockIdx.x * 256 + t; i < n4; i += 256 * 256) {
    float4 v = ((const float4*)src)[i];
    s  += v.x + v.y + v.z + v.w;
    sa += fabsf(v.x) + fabsf(v.y) + fabsf(v.z) + fabsf(v.w);
  }
#pragma unroll
  for (int o = 32; o > 0; o >>= 1) { s += __shfl_xor(s, o, 64); sa += __shfl_xor(sa, o, 64); }
  if (lane == 0) { red[w] = s; red2[w] = sa; }
  __syncthreads();
  if (t == 0) {
    atomicAdd(&stats[2 * m],     red[0] + red[1] + red[2] + red[3]);
    atomicAdd(&stats[2 * m + 1], red2[0] + red2[1] + red2[2] + red2[3]);
  }
}

// ---------------- ternary sign quant ----------------
__global__ void wsign_kernel(const float* wq, const float* wk, const float* wv, const float* wo,
                             ushort* sq, ushort* sk, ushort* sv, ushort* so,
                             const float* stats) {
  int m = blockIdx.y;
  const float* src; ushort* dst; int n4; float cinv;
  if (m == 0)      { src = wq; dst = sq; n4 = 1048576; cinv = 1.f / 4194304.f; }
  else if (m == 1) { src = wk; dst = sk; n4 = 524288;  cinv = 1.f / 2097152.f; }
  else if (m == 2) { src = wv; dst = sv; n4 = 524288;  cinv = 1.f / 2097152.f; }
  else             { src = wo; dst = so; n4 = 1048576; cinv = 1.f / 4194304.f; }
  float e = stats[2 * m] * cinv;
  for (int i = blockIdx.x * 256 + threadIdx.x; i < n4; i += 1024 * 256) {
    float4 v = ((const float4*)src)[i];
    ushort4 o;
    o.x = v.x > e ? 0x3F80 : (v.x < e ? 0xBF80 : 0);
    o.y = v.y > e ? 0x3F80 : (v.y < e ? 0xBF80 : 0);
    o.z = v.z > e ? 0x3F80 : (v.z < e ? 0xBF80 : 0);
    o.w = v.w > e ? 0x3F80 : (v.w < e ? 0xBF80 : 0);
    ((ushort4*)dst)[i] = o;
  }
}

// ---------------- RoPE tables ----------------
__global__ void ropetab_kernel(float* ct, float* st) {
  int s = blockIdx.x, j = threadIdx.x;
  float invf = powf(10000.f, -(float)j * (1.f / 64.f));
  float a = (float)s * invf;
  ct[s * 64 + j] = cosf(a);
  st[s * 64 + j] = sinf(a);
}

// ---------------- fused RMSNorm + activation quant ----------------
DI void quant_one(const float* xs, const float* __restrict__ wt, bf16* __restrict__ a,
                  float* __restrict__ r, int row, int t, int lane, int w, float* red) {
  float4 w0 = ((const float4*)wt)[t * 2], w1 = ((const float4*)wt)[t * 2 + 1];
  float wv[8] = {w0.x, w0.y, w0.z, w0.w, w1.x, w1.y, w1.z, w1.w};
  float y[8]; float am = 0.f;
#pragma unroll
  for (int e = 0; e < 8; ++e) {
    y[e] = clampf(wv[e] * xs[e], -50.f, 50.f);
    am = fmaxf(am, fabsf(y[e]));
  }
  float mx = block_max(am, red, lane, w);
  float maxval = fmaxf(mx, 1e-4f);
  float sc = 127.f / maxval;
  bf16x8 q;
#pragma unroll
  for (int e = 0; e < 8; ++e) {
    float n = rintf(y[e] * sc);
    n = clampf(n, -128.f, 127.f);
    q[e] = (bf16)n;
  }
  *(bf16x8*)(a + (size_t)row * 2048 + t * 8) = q;
  if (t == 0) r[row] = maxval * (1.f / 127.f);
}

template <int NW>
__launch_bounds__(256)
__global__ void rqnorm_kernel(const float* __restrict__ x,
                              const float* __restrict__ w0, const float* __restrict__ w1,
                              const float* __restrict__ w2,
                              bf16* a0, bf16* a1, bf16* a2,
                              float* r0, float* r1, float* r2) {
  __shared__ float red[4];
  int t = threadIdx.x, lane = t & 63, w = t >> 6;
  int row = blockIdx.x;
  const float* xr = x + (size_t)row * 2048;
  float4 u0 = ((const float4*)xr)[t * 2], u1 = ((const float4*)xr)[t * 2 + 1];
  float xs[8] = {u0.x, u0.y, u0.z, u0.w, u1.x, u1.y, u1.z, u1.w};
  float ss = 0.f;
#pragma unroll
  for (int e = 0; e < 8; ++e) { xs[e] = clampf(xs[e], -100.f, 100.f); ss += xs[e] * xs[e]; }
  float tot = block_sum(ss, red, lane, w);
  float var = fmaxf(tot * (1.f / 2048.f), 1e-5f);
  float inv = 1.f / sqrtf(var + 1e-5f);
#pragma unroll
  for (int e = 0; e < 8; ++e) xs[e] = clampf(xs[e] * inv, -10.f, 10.f);
  quant_one(xs, w0, a0, r0, row, t, lane, w, red);
  if (NW > 1) quant_one(xs, w1, a1, r1, row, t, lane, w, red);
  if (NW > 2) quant_one(xs, w2, a2, r2, row, t, lane, w, red);
}

// ---------------- GEMM core: 128x128 tile, XOR-swizzled LDS ----------------
// LDS tiles [128 rows][64 cols], 8 chunks/row; chunk c of row r lives at c^(r&7).
// Staging keeps gl_lds16 (wave-uniform base + lane*16) by permuting the GLOBAL column.
DI void mm_core(const bf16* __restrict__ Ag0, const bf16* __restrict__ Bg0,
                bf16* As, bf16* Bs, int w, int lane, f32x4 acc[2][8]) {
  int l15 = lane & 15, quad = lane >> 4;
  int srow = w * 8 + (lane >> 3);
  int sc_p = (lane & 7) * 8;                       // physical LDS chunk
  int sc_g = ((lane & 7) ^ (lane >> 3)) * 8;       // pre-permuted global chunk
  const bf16* Ag = Ag0 + (size_t)srow * 2048 + sc_g;
  const bf16* Bg = Bg0 + (size_t)srow * 2048 + sc_g;
  bf16* Al = As + srow * 64 + sc_p;
  bf16* Bl = Bs + srow * 64 + sc_p;
  for (int kt = 0; kt < 32; ++kt) {
    size_t kb = (size_t)kt * 64;
#pragma unroll
    for (int i = 0; i < 4; ++i) {
      gl_lds16(Al + i * 32 * 64, Ag + (size_t)i * 32 * 2048 + kb);
      gl_lds16(Bl + i * 32 * 64, Bg + (size_t)i * 32 * 2048 + kb);
    }
    __syncthreads();
#pragma unroll
    for (int kc = 0; kc < 2; ++kc) {
      bf16x8 af[2], bfr[8];
#pragma unroll
      for (int mt = 0; mt < 2; ++mt)
        af[mt] = *(const bf16x8*)(As + (w * 32 + mt * 16 + l15) * 64 +
                                  (((kc * 4 + quad) ^ (l15 & 7)) * 8));
#pragma unroll
      for (int nt = 0; nt < 8; ++nt)
        bfr[nt] = *(const bf16x8*)(Bs + (nt * 16 + l15) * 64 +
                                   (((kc * 4 + quad) ^ (l15 & 7)) * 8));
#pragma unroll
      for (int mt = 0; mt < 2; ++mt)
#pragma unroll
        for (int nt = 0; nt < 8; ++nt)
          acc[mt][nt] = __builtin_amdgcn_mfma_f32_16x16x32_bf16(af[mt], bfr[nt], acc[mt][nt], 0, 0, 0);
    }
    __syncthreads();
  }
}

// ---------------- fused QKV projection GEMM ----------------
// blockIdx.x: 0..15 -> Q (RoPE epilogue), 16..23 -> K (RoPE), 24..31 -> V (fp32 out).
// Sign matrices SQ|SK|SV are contiguous: one B base, row offset per branch.
__launch_bounds__(256, 2)
__global__ void qkv_gemm(const bf16* __restrict__ Aq, const bf16* __restrict__ Ak,
                         const bf16* __restrict__ Av, const bf16* __restrict__ Ball,
                         const float* __restrict__ rq, const float* __restrict__ rk,
                         const float* __restrict__ rv, const float* __restrict__ stats,
                         bf16* __restrict__ qr, bf16* __restrict__ kr,
                         float* __restrict__ vlin,
                         const float* __restrict__ ct, const float* __restrict__ st) {
  __shared__ bf16 As[128 * 64];
  __shared__ bf16 Bs[128 * 64];
  int t = threadIdx.x, w = t >> 6, lane = t & 63;
  int l15 = lane & 15, quad = lane >> 4;
  int x = blockIdx.x, m0 = blockIdx.y * 128;
  const bf16* A; const float* rs; float sw; int brow0;
  if (x < 16)      { A = Aq; rs = rq; sw = stats[1] * (1.f / 4194304.f); brow0 = x * 128; }
  else if (x < 24) { A = Ak; rs = rk; sw = stats[3] * (1.f / 2097152.f); brow0 = 2048 + (x - 16) * 128; }
  else             { A = Av; rs = rv; sw = stats[5] * (1.f / 2097152.f); brow0 = 3072 + (x - 24) * 128; }
  sw = fmaxf(sw, 1e-8f);
  f32x4 acc[2][8] = {};
  mm_core(A + (size_t)m0 * 2048, Ball + (size_t)brow0 * 2048, As, Bs, w, lane, acc);

  if (x < 24) {
    bf16* outb = (x < 16) ? qr : kr;
    int h = (x < 16) ? x : x - 16;
    int nh = (x < 16) ? 16 : 8;
#pragma unroll
    for (int mt = 0; mt < 2; ++mt)
#pragma unroll
      for (int r = 0; r < 4; ++r) {
        int row = m0 + w * 32 + mt * 16 + quad * 4 + r;
        float rsc = rs[row] * sw;
        int s = row & 2047, b = row >> 11;
        size_t base = ((size_t)(b * nh + h) * 2048 + s) * 128;
#pragma unroll
        for (int nt = 0; nt < 4; ++nt) {
          int d = nt * 16 + l15;
          float x1 = acc[mt][nt][r] * rsc;
          float x2 = acc[mt][nt + 4][r] * rsc;
          float c = ct[s * 64 + d], sn = st[s * 64 + d];
          outb[base + d]      = (bf16)(x1 * c - x2 * sn);
          outb[base + d + 64] = (bf16)(x2 * c + x1 * sn);
        }
      }
  } else {
    int n0 = (x - 24) * 128;
#pragma unroll
    for (int mt = 0; mt < 2; ++mt)
#pragma unroll
      for (int r = 0; r < 4; ++r) {
        int row = m0 + w * 32 + mt * 16 + quad * 4 + r;
        float rsc = rs[row] * sw;
#pragma unroll
        for (int nt = 0; nt < 8; ++nt)
          vlin[(size_t)row * 1024 + n0 + nt * 16 + l15] = acc[mt][nt][r] * rsc;
      }
  }
}

// ---------------- O projection GEMM ----------------
__launch_bounds__(256, 2)
__global__ void gemm_o(const bf16* __restrict__ A, const bf16* __restrict__ Bw,
                       const float* __restrict__ rs, const float* __restrict__ stats,
                       float* __restrict__ out) {
  __shared__ bf16 As[128 * 64];
  __shared__ bf16 Bs[128 * 64];
  int t = threadIdx.x, w = t >> 6, lane = t & 63;
  int l15 = lane & 15, quad = lane >> 4;
  int m0 = blockIdx.y * 128, n0 = blockIdx.x * 128;
  f32x4 acc[2][8] = {};
  mm_core(A + (size_t)m0 * 2048, Bw + (size_t)n0 * 2048, As, Bs, w, lane, acc);
  float sw = fmaxf(stats[7] * (1.f / 4194304.f), 1e-8f);
#pragma unroll
  for (int mt = 0; mt < 2; ++mt)
#pragma unroll
    for (int r = 0; r < 4; ++r) {
      int row = m0 + w * 32 + mt * 16 + quad * 4 + r;
      float rsc = rs[row] * sw;
#pragma unroll
      for (int nt = 0; nt < 8; ++nt)
        out[(size_t)row * 2048 + n0 + nt * 16 + l15] = acc[mt][nt][r] * rsc;
    }
}

// ---------------- V transpose ----------------
__global__ void vtrans_kernel(const float* __restrict__ v_lin, bf16* __restrict__ v_t) {
  __shared__ float tile[64][65];
  int t = threadIdx.x, c = t & 63, rq = t >> 6;
  int ct0 = blockIdx.x * 64, tt0 = blockIdx.y * 64;
#pragma unroll
  for (int i = 0; i < 16; ++i) {
    int r = rq * 16 + i;
    tile[r][c] = v_lin[(size_t)(tt0 + r) * 1024 + ct0 + c];
  }
  __syncthreads();
  int token = tt0 + c;
  int b = token >> 11, s = token & 2047;
#pragma unroll
  for (int i = 0; i < 16; ++i) {
    int cg = ct0 + rq * 16 + i;
    int kvh = cg >> 7, d = cg & 127;
    v_t[((size_t)(b * 8 + kvh) * 128 + d) * 2048 + s] = (bf16)tile[c][rq * 16 + i];
  }
}

// ---------------- flash attention ----------------
// q-tile 128, k-tile 64, double-buffered K/V (80KB LDS, 2 blocks/CU),
// ONE barrier per iteration (Ps is wave-private: wave w touches rows w*32..+31 only),
// XOR-swizzled Ks(16-chunk)/Vs(8)/Ps(8) tiles, mask prefetched to registers.
__launch_bounds__(256, 2)
__global__ void attn_kernel(const bf16* __restrict__ Q, const bf16* __restrict__ Kc,
                            const bf16* __restrict__ Vt, const float* __restrict__ mask,
                            float* __restrict__ Oout) {
  constexpr float scale = 0.08838834764831845f; // 1/sqrt(128)
  __shared__ bf16 Ks[2][64 * 128];
  __shared__ bf16 Vs[2][128 * 64];
  __shared__ bf16 Ps[128 * 64];
  int t = threadIdx.x, w = t >> 6, lane = t & 63;
  int l15 = lane & 15, quad = lane >> 4;
  int bh = blockIdx.y, b = bh >> 4, h = bh & 15, kvh = h >> 1;
  int q0 = blockIdx.x * 128;
  const bf16* Qb = Q + (size_t)(b * 16 + h) * 2048 * 128;
  const bf16* Kb = Kc + (size_t)(b * 8 + kvh) * 2048 * 128;
  const bf16* Vb = Vt + (size_t)(b * 8 + kvh) * 128 * 2048;

  // Q fragments (held in registers for the whole kernel)
  bf16x8 qf[2][4];
  int qw = q0 + w * 32;
#pragma unroll
  for (int mt = 0; mt < 2; ++mt)
#pragma unroll
    for (int kc = 0; kc < 4; ++kc)
      qf[mt][kc] = *(const bf16x8*)(Qb + (size_t)(qw + mt * 16 + l15) * 128 + kc * 32 + quad * 8);

  f32x4 Oa[2][8] = {};
  float mrow[2][4], lrow[2][4];
#pragma unroll
  for (int mt = 0; mt < 2; ++mt)
#pragma unroll
    for (int r = 0; r < 4; ++r) { mrow[mt][r] = -1e30f; lrow[mt][r] = 0.f; }

  // staging indices (swizzle: permute GLOBAL chunk, keep LDS lane-contiguous)
  int krow = w * 4 + quad;
  int kcol_p = l15 * 8;
  int kcol_g = (l15 ^ krow) * 8;                   // Ks rows: 16 chunks, xor r&15
  int vrow = w * 8 + (lane >> 3);
  int vc_p = (lane & 7) * 8;
  int vc_g = ((lane & 7) ^ (lane >> 3)) * 8;       // Vs rows: 8 chunks, xor r&7

  auto stage = [&](int buf, int kt) {
    int kk0 = kt * 64;
#pragma unroll
    for (int i = 0; i < 4; ++i)
      gl_lds16(&Ks[buf][(i * 16 + krow) * 128 + kcol_p],
               Kb + (size_t)(kk0 + i * 16 + krow) * 128 + kcol_g);
#pragma unroll
    for (int i = 0; i < 4; ++i)
      gl_lds16(&Vs[buf][(i * 32 + vrow) * 64 + vc_p],
               Vb + (size_t)(i * 32 + vrow) * 2048 + kk0 + vc_g);
  };

  stage(0, 0);

  for (int kt = 0; kt < 32; ++kt) {
    int cur = kt & 1;
    int kk0 = kt * 64;
    __syncthreads();                // drains prefetch issued one full iter ago
    if (kt < 31) stage(cur ^ 1, kt + 1);

    // prefetch mask tile into registers (overlaps the QK MFMAs)
    float mv[2][4][4];
#pragma unroll
    for (int mt = 0; mt < 2; ++mt)
#pragma unroll
      for (int r = 0; r < 4; ++r) {
        const float* mp = mask + (size_t)(q0 + w * 32 + mt * 16 + quad * 4 + r) * 2048 + kk0 + l15;
#pragma unroll
        for (int nt = 0; nt < 4; ++nt) mv[mt][nt][r] = mp[nt * 16];
      }

    // S = Q K^T
    f32x4 Sacc[2][4] = {};
#pragma unroll
    for (int kc = 0; kc < 4; ++kc) {
      bf16x8 kf[4];
#pragma unroll
      for (int nt = 0; nt < 4; ++nt)
        kf[nt] = *(const bf16x8*)(&Ks[cur][(nt * 16 + l15) * 128 + (((kc * 4 + quad) ^ l15) * 8)]);
#pragma unroll
      for (int mt = 0; mt < 2; ++mt)
#pragma unroll
        for (int nt = 0; nt < 4; ++nt)
          Sacc[mt][nt] = __builtin_amdgcn_mfma_f32_16x16x32_bf16(qf[mt][kc], kf[nt], Sacc[mt][nt], 0, 0, 0);
    }

    // online softmax
#pragma unroll
    for (int mt = 0; mt < 2; ++mt) {
      f32x4 av;
#pragma unroll
      for (int r = 0; r < 4; ++r) {
#pragma unroll
        for (int nt = 0; nt < 4; ++nt)
          Sacc[mt][nt][r] = Sacc[mt][nt][r] * scale + mv[mt][nt][r];
        float mx = fmaxf(fmaxf(Sacc[mt][0][r], Sacc[mt][1][r]),
                         fmaxf(Sacc[mt][2][r], Sacc[mt][3][r]));
        mx = fmaxf(mx, __shfl_xor(mx, 1, 16));
        mx = fmaxf(mx, __shfl_xor(mx, 2, 16));
        mx = fmaxf(mx, __shfl_xor(mx, 4, 16));
        mx = fmaxf(mx, __shfl_xor(mx, 8, 16));
        float mnew = fmaxf(mrow[mt][r], mx);
        float alpha = __expf(mrow[mt][r] - mnew);
        mrow[mt][r] = mnew;
        float rsum = 0.f;
#pragma unroll
        for (int nt = 0; nt < 4; ++nt) {
          float p = __expf(Sacc[mt][nt][r] - mnew);
          Sacc[mt][nt][r] = p;
          rsum += p;
        }
        rsum += __shfl_xor(rsum, 1, 16);
        rsum += __shfl_xor(rsum, 2, 16);
        rsum += __shfl_xor(rsum, 4, 16);
        rsum += __shfl_xor(rsum, 8, 16);
        lrow[mt][r] = lrow[mt][r] * alpha + rsum;
        av[r] = alpha;
        // Ps write, swizzled: col chunk c = nt*2 + (l15>>3), stored at c ^ (q&7)
        int qloc = w * 32 + mt * 16 + quad * 4 + r;
        int pb = qloc * 64 + (l15 & 7);
#pragma unroll
        for (int nt = 0; nt < 4; ++nt) {
          int p = ((nt * 2 + (l15 >> 3)) ^ (qloc & 7)) * 8;
          Ps[pb + p] = (bf16)Sacc[mt][nt][r];
        }
      }
#pragma unroll
      for (int nt = 0; nt < 8; ++nt) Oa[mt][nt] *= av;   // v_pk_mul_f32 pairs
    }

    // O += P V  (Ps rows w*32..w*32+31 are wave-private: no barrier needed)
#pragma unroll
    for (int kc = 0; kc < 2; ++kc) {
      bf16x8 pf[2];
#pragma unroll
      for (int mt = 0; mt < 2; ++mt)
        pf[mt] = *(const bf16x8*)(&Ps[(w * 32 + mt * 16 + l15) * 64 +
                                      (((kc * 4 + quad) ^ (l15 & 7)) * 8)]);
#pragma unroll
      for (int nt = 0; nt < 8; ++nt) {
        bf16x8 vf = *(const bf16x8*)(&Vs[cur][(nt * 16 + l15) * 64 +
                                              (((kc * 4 + quad) ^ (l15 & 7)) * 8)]);
#pragma unroll
        for (int mt = 0; mt < 2; ++mt)
          Oa[mt][nt] = __builtin_amdgcn_mfma_f32_16x16x32_bf16(pf[mt], vf, Oa[mt][nt], 0, 0, 0);
      }
    }
  }

#pragma unroll
  for (int mt = 0; mt < 2; ++mt)
#pragma unroll
    for (int r = 0; r < 4; ++r) {
      float inv = 1.f / lrow[mt][r];
      int token = b * 2048 + q0 + w * 32 + mt * 16 + quad * 4 + r;
#pragma unroll
      for (int nt = 0; nt < 8; ++nt)
        Oout[(size_t)token * 2048 + h * 128 + nt * 16 + l15] = Oa[mt][nt][r] * inv;
    }
}

// ---------------- launch ----------------
extern "C" void kernel_launch(void* const* d_in, const int* in_sizes, int n_in,
                              void* d_out, int out_size, void* d_ws, size_t ws_size,
                              hipStream_t stream) {
  const float* hidden = (const float*)d_in[0];
  const float* mask   = (const float*)d_in[1];
  const float* wq = (const float*)d_in[2];
  const float* wk = (const float*)d_in[3];
  const float* wv = (const float*)d_in[4];
  const float* wo = (const float*)d_in[5];
  const float* nq = (const float*)d_in[6];
  const float* nk = (const float*)d_in[7];
  const float* nv = (const float*)d_in[8];
  const float* no = (const float*)d_in[9];
  float* out = (float*)d_out;
  char* ws = (char*)d_ws;

  constexpr size_t O_STATS = 0;
  constexpr size_t O_CT    = 256;
  constexpr size_t O_ST    = O_CT + 524288;
  constexpr size_t O_SQ    = O_ST + 524288;   // SQ|SK|SV|SO contiguous (B base for fused gemm)
  constexpr size_t O_SK    = O_SQ + 8388608;
  constexpr size_t O_SV    = O_SK + 4194304;
  constexpr size_t O_SO    = O_SV + 4194304;
  constexpr size_t O_RSQ   = O_SO + 8388608;
  constexpr size_t O_RSK   = O_RSQ + 16384;
  constexpr size_t O_RSV   = O_RSK + 16384;
  constexpr size_t O_RSO   = O_RSV + 16384;
  constexpr size_t O_AQQ   = O_RSO + 16384;
  constexpr size_t O_AQK   = O_AQQ + 16777216;
  constexpr size_t O_AQV   = O_AQK + 16777216;
  constexpr size_t O_QR    = O_AQV + 16777216;
  constexpr size_t O_KR    = O_QR + 16777216;
  constexpr size_t O_VT    = O_KR + 8388608;
  constexpr size_t O_VLIN  = O_AQQ;           // alias, lifetime after qkv_gemm reads AQQ? no:
  // NOTE: VLIN must not alias AQQ/AQK/AQV (qkv_gemm reads them while writing VLIN).
  constexpr size_t O_VLIN2 = O_VT + 8388608;  // fp32 [4096,1024] = 16777216
  constexpr size_t O_ATTN  = O_AQQ;           // fp32 [4096,2048] (after attn inputs built)
  constexpr size_t O_AQO   = O_AQV;

  float* stats = (float*)(ws + O_STATS);
  float* ct = (float*)(ws + O_CT);
  float* st = (float*)(ws + O_ST);

  hipMemsetAsync(ws + O_STATS, 0, 256, stream);

  wstats_kernel<<<dim3(256, 4), 256, 0, stream>>>(wq, wk, wv, wo, stats);
  wsign_kernel<<<dim3(1024, 4), 256, 0, stream>>>(wq, wk, wv, wo,
      (ushort*)(ws + O_SQ), (ushort*)(ws + O_SK), (ushort*)(ws + O_SV), (ushort*)(ws + O_SO), stats);
  ropetab_kernel<<<dim3(2048), 64, 0, stream>>>(ct, st);

  rqnorm_kernel<3><<<dim3(4096), 256, 0, stream>>>(hidden, nq, nk, nv,
      (bf16*)(ws + O_AQQ), (bf16*)(ws + O_AQK), (bf16*)(ws + O_AQV),
      (float*)(ws + O_RSQ), (float*)(ws + O_RSK), (float*)(ws + O_RSV));

  qkv_gemm<<<dim3(32, 32), 256, 0, stream>>>(
      (const bf16*)(ws + O_AQQ), (const bf16*)(ws + O_AQK), (const bf16*)(ws + O_AQV),
      (const bf16*)(ws + O_SQ),
      (const float*)(ws + O_RSQ), (const float*)(ws + O_RSK), (const float*)(ws + O_RSV),
      stats, (bf16*)(ws + O_QR), (bf16*)(ws + O_KR), (float*)(ws + O_VLIN2), ct, st);

  vtrans_kernel<<<dim3(16, 64), 256, 0, stream>>>((const float*)(ws + O_VLIN2), (bf16*)(ws + O_VT));

  attn_kernel<<<dim3(16, 32), 256, 0, stream>>>(
      (const bf16*)(ws + O_QR), (const bf16*)(ws + O_KR), (const bf16*)(ws + O_VT),
      mask, (float*)(ws + O_ATTN));

  rqnorm_kernel<1><<<dim3(4096), 256, 0, stream>>>((const float*)(ws + O_ATTN), no, no, no,
      (bf16*)(ws + O_AQO), (bf16*)(ws + O_AQO), (bf16*)(ws + O_AQO),
      (float*)(ws + O_RSO), (float*)(ws + O_RSO), (float*)(ws + O_RSO));

  gemm_o<<<dim3(16, 32), 256, 0, stream>>>(
      (const bf16*)(ws + O_AQO), (const bf16*)(ws + O_SO), (float*)(ws + O_RSO), stats, out);

  (void)in_sizes; (void)n_in; (void)out_size; (void)ws_size; (void)O_VLIN;
}

// Round 4
// 437.317 us; speedup vs baseline: 1.3359x; 1.1466x over previous
//
#include <hip/hip_runtime.h>

// BitNetAttention on MI355X (gfx950).
// Bitlinear matmuls are integer-exact in bf16 MFMA (activations = n*(max/127),
// weights = sign*scale; integer sums < 2^24 accumulate exactly in fp32).
// R1: XOR-swizzled LDS (conflicts 4.9e7 -> 0), fused QKV GEMM.
// R2/R3: attention computes S^T = K*Q^T so softmax reductions are IN-LANE
//     (register tree + 2 cross-quad shuffles) instead of 64 cross-lane
//     swizzles/lane/iter; float4 mask prefetched a full phase early;
//     Ps via ds_write_b64; O^T epilogue with float4 stores.
//     (R3 fixes qf[qt] -> qf[qt][kc] typo.)

#define DI __device__ __forceinline__

using bf16   = __bf16;
using bf16x4 = __attribute__((ext_vector_type(4))) __bf16;
using bf16x8 = __attribute__((ext_vector_type(8))) __bf16;
using f32x4  = __attribute__((ext_vector_type(4))) float;

DI void gl_lds16(void* lds, const void* g) {
  __builtin_amdgcn_global_load_lds((const __attribute__((address_space(1))) void*)g,
                                   (__attribute__((address_space(3))) void*)lds, 16, 0, 0);
}
DI float clampf(float x, float lo, float hi) { return fminf(fmaxf(x, lo), hi); }

DI float block_sum(float v, float* red, int lane, int w) {
#pragma unroll
  for (int o = 32; o > 0; o >>= 1) v += __shfl_xor(v, o, 64);
  __syncthreads();
  if (lane == 0) red[w] = v;
  __syncthreads();
  return red[0] + red[1] + red[2] + red[3];
}
DI float block_max(float v, float* red, int lane, int w) {
#pragma unroll
  for (int o = 32; o > 0; o >>= 1) v = fmaxf(v, __shfl_xor(v, o, 64));
  __syncthreads();
  if (lane == 0) red[w] = v;
  __syncthreads();
  return fmaxf(fmaxf(red[0], red[1]), fmaxf(red[2], red[3]));
}

// ---------------- weight stats ----------------
__global__ void wstats_kernel(const float* wq, const float* wk, const float* wv,
                              const float* wo, float* stats) {
  __shared__ float red[4], red2[4];
  int t = threadIdx.x, lane = t & 63, w = t >> 6;
  int m = blockIdx.y;
  const float* src; int n4;
  if (m == 0)      { src = wq; n4 = 1048576; }
  else if (m == 1) { src = wk; n4 = 524288;  }
  else if (m == 2) { src = wv; n4 = 524288;  }
  else             { src = wo; n4 = 1048576; }
  float s = 0.f, sa = 0.f;
  for (int i = blockIdx.x * 256 + t; i < n4; i += 256 * 256) {
    float4 v = ((const float4*)src)[i];
    s  += v.x + v.y + v.z + v.w;
    sa += fabsf(v.x) + fabsf(v.y) + fabsf(v.z) + fabsf(v.w);
  }
#pragma unroll
  for (int o = 32; o > 0; o >>= 1) { s += __shfl_xor(s, o, 64); sa += __shfl_xor(sa, o, 64); }
  if (lane == 0) { red[w] = s; red2[w] = sa; }
  __syncthreads();
  if (t == 0) {
    atomicAdd(&stats[2 * m],     red[0] + red[1] + red[2] + red[3]);
    atomicAdd(&stats[2 * m + 1], red2[0] + red2[1] + red2[2] + red2[3]);
  }
}

// ---------------- ternary sign quant ----------------
__global__ void wsign_kernel(const float* wq, const float* wk, const float* wv, const float* wo,
                             ushort* sq, ushort* sk, ushort* sv, ushort* so,
                             const float* stats) {
  int m = blockIdx.y;
  const float* src; ushort* dst; int n4; float cinv;
  if (m == 0)      { src = wq; dst = sq; n4 = 1048576; cinv = 1.f / 4194304.f; }
  else if (m == 1) { src = wk; dst = sk; n4 = 524288;  cinv = 1.f / 2097152.f; }
  else if (m == 2) { src = wv; dst = sv; n4 = 524288;  cinv = 1.f / 2097152.f; }
  else             { src = wo; dst = so; n4 = 1048576; cinv = 1.f / 4194304.f; }
  float e = stats[2 * m] * cinv;
  for (int i = blockIdx.x * 256 + threadIdx.x; i < n4; i += 1024 * 256) {
    float4 v = ((const float4*)src)[i];
    ushort4 o;
    o.x = v.x > e ? 0x3F80 : (v.x < e ? 0xBF80 : 0);
    o.y = v.y > e ? 0x3F80 : (v.y < e ? 0xBF80 : 0);
    o.z = v.z > e ? 0x3F80 : (v.z < e ? 0xBF80 : 0);
    o.w = v.w > e ? 0x3F80 : (v.w < e ? 0xBF80 : 0);
    ((ushort4*)dst)[i] = o;
  }
}

// ---------------- RoPE tables ----------------
__global__ void ropetab_kernel(float* ct, float* st) {
  int s = blockIdx.x, j = threadIdx.x;
  float invf = powf(10000.f, -(float)j * (1.f / 64.f));
  float a = (float)s * invf;
  ct[s * 64 + j] = cosf(a);
  st[s * 64 + j] = sinf(a);
}

// ---------------- fused RMSNorm + activation quant ----------------
DI void quant_one(const float* xs, const float* __restrict__ wt, bf16* __restrict__ a,
                  float* __restrict__ r, int row, int t, int lane, int w, float* red) {
  float4 w0 = ((const float4*)wt)[t * 2], w1 = ((const float4*)wt)[t * 2 + 1];
  float wv[8] = {w0.x, w0.y, w0.z, w0.w, w1.x, w1.y, w1.z, w1.w};
  float y[8]; float am = 0.f;
#pragma unroll
  for (int e = 0; e < 8; ++e) {
    y[e] = clampf(wv[e] * xs[e], -50.f, 50.f);
    am = fmaxf(am, fabsf(y[e]));
  }
  float mx = block_max(am, red, lane, w);
  float maxval = fmaxf(mx, 1e-4f);
  float sc = 127.f / maxval;
  bf16x8 q;
#pragma unroll
  for (int e = 0; e < 8; ++e) {
    float n = rintf(y[e] * sc);
    n = clampf(n, -128.f, 127.f);
    q[e] = (bf16)n;
  }
  *(bf16x8*)(a + (size_t)row * 2048 + t * 8) = q;
  if (t == 0) r[row] = maxval * (1.f / 127.f);
}

template <int NW>
__launch_bounds__(256)
__global__ void rqnorm_kernel(const float* __restrict__ x,
                              const float* __restrict__ w0, const float* __restrict__ w1,
                              const float* __restrict__ w2,
                              bf16* a0, bf16* a1, bf16* a2,
                              float* r0, float* r1, float* r2) {
  __shared__ float red[4];
  int t = threadIdx.x, lane = t & 63, w = t >> 6;
  int row = blockIdx.x;
  const float* xr = x + (size_t)row * 2048;
  float4 u0 = ((const float4*)xr)[t * 2], u1 = ((const float4*)xr)[t * 2 + 1];
  float xs[8] = {u0.x, u0.y, u0.z, u0.w, u1.x, u1.y, u1.z, u1.w};
  float ss = 0.f;
#pragma unroll
  for (int e = 0; e < 8; ++e) { xs[e] = clampf(xs[e], -100.f, 100.f); ss += xs[e] * xs[e]; }
  float tot = block_sum(ss, red, lane, w);
  float var = fmaxf(tot * (1.f / 2048.f), 1e-5f);
  float inv = 1.f / sqrtf(var + 1e-5f);
#pragma unroll
  for (int e = 0; e < 8; ++e) xs[e] = clampf(xs[e] * inv, -10.f, 10.f);
  quant_one(xs, w0, a0, r0, row, t, lane, w, red);
  if (NW > 1) quant_one(xs, w1, a1, r1, row, t, lane, w, red);
  if (NW > 2) quant_one(xs, w2, a2, r2, row, t, lane, w, red);
}

// ---------------- GEMM core: 128x128 tile, XOR-swizzled LDS ----------------
DI void mm_core(const bf16* __restrict__ Ag0, const bf16* __restrict__ Bg0,
                bf16* As, bf16* Bs, int w, int lane, f32x4 acc[2][8]) {
  int l15 = lane & 15, quad = lane >> 4;
  int srow = w * 8 + (lane >> 3);
  int sc_p = (lane & 7) * 8;
  int sc_g = ((lane & 7) ^ (lane >> 3)) * 8;
  const bf16* Ag = Ag0 + (size_t)srow * 2048 + sc_g;
  const bf16* Bg = Bg0 + (size_t)srow * 2048 + sc_g;
  bf16* Al = As + srow * 64 + sc_p;
  bf16* Bl = Bs + srow * 64 + sc_p;
  for (int kt = 0; kt < 32; ++kt) {
    size_t kb = (size_t)kt * 64;
#pragma unroll
    for (int i = 0; i < 4; ++i) {
      gl_lds16(Al + i * 32 * 64, Ag + (size_t)i * 32 * 2048 + kb);
      gl_lds16(Bl + i * 32 * 64, Bg + (size_t)i * 32 * 2048 + kb);
    }
    __syncthreads();
#pragma unroll
    for (int kc = 0; kc < 2; ++kc) {
      bf16x8 af[2], bfr[8];
#pragma unroll
      for (int mt = 0; mt < 2; ++mt)
        af[mt] = *(const bf16x8*)(As + (w * 32 + mt * 16 + l15) * 64 +
                                  (((kc * 4 + quad) ^ (l15 & 7)) * 8));
#pragma unroll
      for (int nt = 0; nt < 8; ++nt)
        bfr[nt] = *(const bf16x8*)(Bs + (nt * 16 + l15) * 64 +
                                   (((kc * 4 + quad) ^ (l15 & 7)) * 8));
#pragma unroll
      for (int mt = 0; mt < 2; ++mt)
#pragma unroll
        for (int nt = 0; nt < 8; ++nt)
          acc[mt][nt] = __builtin_amdgcn_mfma_f32_16x16x32_bf16(af[mt], bfr[nt], acc[mt][nt], 0, 0, 0);
    }
    __syncthreads();
  }
}

// ---------------- fused QKV projection GEMM ----------------
__launch_bounds__(256, 2)
__global__ void qkv_gemm(const bf16* __restrict__ Aq, const bf16* __restrict__ Ak,
                         const bf16* __restrict__ Av, const bf16* __restrict__ Ball,
                         const float* __restrict__ rq, const float* __restrict__ rk,
                         const float* __restrict__ rv, const float* __restrict__ stats,
                         bf16* __restrict__ qr, bf16* __restrict__ kr,
                         float* __restrict__ vlin,
                         const float* __restrict__ ct, const float* __restrict__ st) {
  __shared__ bf16 As[128 * 64];
  __shared__ bf16 Bs[128 * 64];
  int t = threadIdx.x, w = t >> 6, lane = t & 63;
  int l15 = lane & 15, quad = lane >> 4;
  int x = blockIdx.x, m0 = blockIdx.y * 128;
  const bf16* A; const float* rs; float sw; int brow0;
  if (x < 16)      { A = Aq; rs = rq; sw = stats[1] * (1.f / 4194304.f); brow0 = x * 128; }
  else if (x < 24) { A = Ak; rs = rk; sw = stats[3] * (1.f / 2097152.f); brow0 = 2048 + (x - 16) * 128; }
  else             { A = Av; rs = rv; sw = stats[5] * (1.f / 2097152.f); brow0 = 3072 + (x - 24) * 128; }
  sw = fmaxf(sw, 1e-8f);
  f32x4 acc[2][8] = {};
  mm_core(A + (size_t)m0 * 2048, Ball + (size_t)brow0 * 2048, As, Bs, w, lane, acc);

  if (x < 24) {
    bf16* outb = (x < 16) ? qr : kr;
    int h = (x < 16) ? x : x - 16;
    int nh = (x < 16) ? 16 : 8;
#pragma unroll
    for (int mt = 0; mt < 2; ++mt)
#pragma unroll
      for (int r = 0; r < 4; ++r) {
        int row = m0 + w * 32 + mt * 16 + quad * 4 + r;
        float rsc = rs[row] * sw;
        int s = row & 2047, b = row >> 11;
        size_t base = ((size_t)(b * nh + h) * 2048 + s) * 128;
#pragma unroll
        for (int nt = 0; nt < 4; ++nt) {
          int d = nt * 16 + l15;
          float x1 = acc[mt][nt][r] * rsc;
          float x2 = acc[mt][nt + 4][r] * rsc;
          float c = ct[s * 64 + d], sn = st[s * 64 + d];
          outb[base + d]      = (bf16)(x1 * c - x2 * sn);
          outb[base + d + 64] = (bf16)(x2 * c + x1 * sn);
        }
      }
  } else {
    int n0 = (x - 24) * 128;
#pragma unroll
    for (int mt = 0; mt < 2; ++mt)
#pragma unroll
      for (int r = 0; r < 4; ++r) {
        int row = m0 + w * 32 + mt * 16 + quad * 4 + r;
        float rsc = rs[row] * sw;
#pragma unroll
        for (int nt = 0; nt < 8; ++nt)
          vlin[(size_t)row * 1024 + n0 + nt * 16 + l15] = acc[mt][nt][r] * rsc;
      }
  }
}

// ---------------- O projection GEMM ----------------
__launch_bounds__(256, 2)
__global__ void gemm_o(const bf16* __restrict__ A, const bf16* __restrict__ Bw,
                       const float* __restrict__ rs, const float* __restrict__ stats,
                       float* __restrict__ out) {
  __shared__ bf16 As[128 * 64];
  __shared__ bf16 Bs[128 * 64];
  int t = threadIdx.x, w = t >> 6, lane = t & 63;
  int l15 = lane & 15, quad = lane >> 4;
  int m0 = blockIdx.y * 128, n0 = blockIdx.x * 128;
  f32x4 acc[2][8] = {};
  mm_core(A + (size_t)m0 * 2048, Bw + (size_t)n0 * 2048, As, Bs, w, lane, acc);
  float sw = fmaxf(stats[7] * (1.f / 4194304.f), 1e-8f);
#pragma unroll
  for (int mt = 0; mt < 2; ++mt)
#pragma unroll
    for (int r = 0; r < 4; ++r) {
      int row = m0 + w * 32 + mt * 16 + quad * 4 + r;
      float rsc = rs[row] * sw;
#pragma unroll
      for (int nt = 0; nt < 8; ++nt)
        out[(size_t)row * 2048 + n0 + nt * 16 + l15] = acc[mt][nt][r] * rsc;
    }
}

// ---------------- V transpose ----------------
__global__ void vtrans_kernel(const float* __restrict__ v_lin, bf16* __restrict__ v_t) {
  __shared__ float tile[64][65];
  int t = threadIdx.x, c = t & 63, rq = t >> 6;
  int ct0 = blockIdx.x * 64, tt0 = blockIdx.y * 64;
#pragma unroll
  for (int i = 0; i < 16; ++i) {
    int r = rq * 16 + i;
    tile[r][c] = v_lin[(size_t)(tt0 + r) * 1024 + ct0 + c];
  }
  __syncthreads();
  int token = tt0 + c;
  int b = token >> 11, s = token & 2047;
#pragma unroll
  for (int i = 0; i < 16; ++i) {
    int cg = ct0 + rq * 16 + i;
    int kvh = cg >> 7, d = cg & 127;
    v_t[((size_t)(b * 8 + kvh) * 128 + d) * 2048 + s] = (bf16)tile[c][rq * 16 + i];
  }
}

// ---------------- flash attention, S^T formulation ----------------
// S^T = K*Q^T: C-layout col=l15=q, row=quad*4+reg=k -> softmax over k is an
// in-lane register tree + 2 cross-quad shuffles per q (vs 64 cross-lane swizzles).
// PV computes O^T (A=V^T frag, B=P from LDS). Mask as float4, prefetched during PV.
__launch_bounds__(256, 2)
__global__ void attn_kernel(const bf16* __restrict__ Q, const bf16* __restrict__ Kc,
                            const bf16* __restrict__ Vt, const float* __restrict__ mask,
                            float* __restrict__ Oout) {
  constexpr float scale = 0.08838834764831845f; // 1/sqrt(128)
  __shared__ bf16 Ks[2][64 * 128];
  __shared__ bf16 Vs[2][128 * 64];
  __shared__ bf16 Ps[128 * 64];
  int t = threadIdx.x, w = t >> 6, lane = t & 63;
  int l15 = lane & 15, quad = lane >> 4;
  int bh = blockIdx.y, b = bh >> 4, h = bh & 15, kvh = h >> 1;
  int q0 = blockIdx.x * 128;
  const bf16* Qb = Q + (size_t)(b * 16 + h) * 2048 * 128;
  const bf16* Kb = Kc + (size_t)(b * 8 + kvh) * 2048 * 128;
  const bf16* Vb = Vt + (size_t)(b * 8 + kvh) * 128 * 2048;

  int qloc = w * 32 + l15;              // local q of qt=0; qt=1 adds 16
  int qg = q0 + qloc;                   // global q position (0..2047)

  // Q fragments as B-operand (n = q)
  bf16x8 qf[2][4];
#pragma unroll
  for (int qt = 0; qt < 2; ++qt)
#pragma unroll
    for (int kc = 0; kc < 4; ++kc)
      qf[qt][kc] = *(const bf16x8*)(Qb + (size_t)(qg + qt * 16) * 128 + kc * 32 + quad * 8);

  f32x4 Oa[8][2] = {};                  // [dt][qt], O^T: row=d, col=q
  float mrow[2] = {-1e30f, -1e30f}, lrow[2] = {0.f, 0.f};

  // staging (unchanged swizzles)
  int krow = w * 4 + quad;
  int kcol_p = l15 * 8;
  int kcol_g = (l15 ^ krow) * 8;
  int vrow = w * 8 + (lane >> 3);
  int vc_p = (lane & 7) * 8;
  int vc_g = ((lane & 7) ^ (lane >> 3)) * 8;

  auto stage = [&](int buf, int kt) {
    int kk0 = kt * 64;
#pragma unroll
    for (int i = 0; i < 4; ++i)
      gl_lds16(&Ks[buf][(i * 16 + krow) * 128 + kcol_p],
               Kb + (size_t)(kk0 + i * 16 + krow) * 128 + kcol_g);
#pragma unroll
    for (int i = 0; i < 4; ++i)
      gl_lds16(&Vs[buf][(i * 32 + vrow) * 64 + vc_p],
               Vb + (size_t)(i * 32 + vrow) * 2048 + kk0 + vc_g);
  };

  stage(0, 0);

  // mask tile for kt=0: mv[qt][k2] = mask[q][k2*16 + quad*4 .. +3]
  f32x4 mv[2][4], mvn[2][4];
#pragma unroll
  for (int qt = 0; qt < 2; ++qt)
#pragma unroll
    for (int k2 = 0; k2 < 4; ++k2)
      mv[qt][k2] = *(const f32x4*)(mask + (size_t)(qg + qt * 16) * 2048 + k2 * 16 + quad * 4);

  for (int kt = 0; kt < 32; ++kt) {
    int cur = kt & 1;
    __syncthreads();                    // drains prefetch issued one iter ago
    if (kt < 31) stage(cur ^ 1, kt + 1);

    // S^T = K Q^T  (A = K frag, B = Q frag)
    f32x4 Sacc[4][2] = {};              // [k2][qt]
#pragma unroll
    for (int kc = 0; kc < 4; ++kc) {
      bf16x8 kf[4];
#pragma unroll
      for (int k2 = 0; k2 < 4; ++k2)
        kf[k2] = *(const bf16x8*)(&Ks[cur][(k2 * 16 + l15) * 128 + (((kc * 4 + quad) ^ l15) * 8)]);
#pragma unroll
      for (int k2 = 0; k2 < 4; ++k2)
#pragma unroll
        for (int qt = 0; qt < 2; ++qt)
          Sacc[k2][qt] = __builtin_amdgcn_mfma_f32_16x16x32_bf16(kf[k2], qf[qt][kc], Sacc[k2][qt], 0, 0, 0);
    }

    // online softmax: per lane, 2 q columns, 16 k values each (in-lane) + cross-quad
#pragma unroll
    for (int qt = 0; qt < 2; ++qt) {
#pragma unroll
      for (int k2 = 0; k2 < 4; ++k2)
#pragma unroll
        for (int r = 0; r < 4; ++r)
          Sacc[k2][qt][r] = Sacc[k2][qt][r] * scale + mv[qt][k2][r];
      f32x4 vm = Sacc[0][qt];
#pragma unroll
      for (int k2 = 1; k2 < 4; ++k2)
#pragma unroll
        for (int r = 0; r < 4; ++r) vm[r] = fmaxf(vm[r], Sacc[k2][qt][r]);
      float mx = fmaxf(fmaxf(vm[0], vm[1]), fmaxf(vm[2], vm[3]));
      mx = fmaxf(mx, __shfl_xor(mx, 16, 64));
      mx = fmaxf(mx, __shfl_xor(mx, 32, 64));
      float mnew = fmaxf(mrow[qt], mx);
      float alpha = __expf(mrow[qt] - mnew);
      mrow[qt] = mnew;
      f32x4 vs = {0.f, 0.f, 0.f, 0.f};
#pragma unroll
      for (int k2 = 0; k2 < 4; ++k2)
#pragma unroll
        for (int r = 0; r < 4; ++r) {
          float p = __expf(Sacc[k2][qt][r] - mnew);
          Sacc[k2][qt][r] = p;
          vs[r] += p;
        }
      float rsum = (vs[0] + vs[1]) + (vs[2] + vs[3]);
      rsum += __shfl_xor(rsum, 16, 64);
      rsum += __shfl_xor(rsum, 32, 64);
      lrow[qt] = lrow[qt] * alpha + rsum;
#pragma unroll
      for (int dt = 0; dt < 8; ++dt) Oa[dt][qt] *= alpha;    // uniform per vector
      // P^T -> Ps[q][k] rows (wave-private), 4 consecutive k per ds_write_b64
      int qr = qloc + qt * 16;
#pragma unroll
      for (int k2 = 0; k2 < 4; ++k2) {
        bf16x4 pk;
#pragma unroll
        for (int r = 0; r < 4; ++r) pk[r] = (bf16)Sacc[k2][qt][r];
        int c = k2 * 2 + (quad >> 1);
        *(bf16x4*)(&Ps[qr * 64 + ((c ^ (qr & 7)) * 8) + (quad & 1) * 4]) = pk;
      }
    }

    // prefetch next mask tile during PV (drained by next barrier's vmcnt wait)
    if (kt < 31) {
      int kk1 = (kt + 1) * 64;
#pragma unroll
      for (int qt = 0; qt < 2; ++qt)
#pragma unroll
        for (int k2 = 0; k2 < 4; ++k2)
          mvn[qt][k2] = *(const f32x4*)(mask + (size_t)(qg + qt * 16) * 2048 + kk1 + k2 * 16 + quad * 4);
    }

    // O^T += V^T P  (A = V^T frag, B = P frag; Ps rows wave-private, no barrier)
#pragma unroll
    for (int kc = 0; kc < 2; ++kc) {
      bf16x8 pf[2];
#pragma unroll
      for (int qt = 0; qt < 2; ++qt)
        pf[qt] = *(const bf16x8*)(&Ps[(qloc + qt * 16) * 64 + (((kc * 4 + quad) ^ (l15 & 7)) * 8)]);
#pragma unroll
      for (int dt = 0; dt < 8; ++dt) {
        bf16x8 vf = *(const bf16x8*)(&Vs[cur][(dt * 16 + l15) * 64 +
                                              (((kc * 4 + quad) ^ (l15 & 7)) * 8)]);
#pragma unroll
        for (int qt = 0; qt < 2; ++qt)
          Oa[dt][qt] = __builtin_amdgcn_mfma_f32_16x16x32_bf16(vf, pf[qt], Oa[dt][qt], 0, 0, 0);
      }
    }

#pragma unroll
    for (int qt = 0; qt < 2; ++qt)
#pragma unroll
      for (int k2 = 0; k2 < 4; ++k2) mv[qt][k2] = mvn[qt][k2];
  }

  // epilogue: per lane 2 q columns, d = dt*16 + quad*4 + r (4 consecutive -> float4)
#pragma unroll
  for (int qt = 0; qt < 2; ++qt) {
    float inv = 1.f / lrow[qt];
    int token = b * 2048 + qg + qt * 16;
#pragma unroll
    for (int dt = 0; dt < 8; ++dt) {
      f32x4 o = Oa[dt][qt] * inv;
      *(f32x4*)(Oout + (size_t)token * 2048 + h * 128 + dt * 16 + quad * 4) = o;
    }
  }
}

// ---------------- launch ----------------
extern "C" void kernel_launch(void* const* d_in, const int* in_sizes, int n_in,
                              void* d_out, int out_size, void* d_ws, size_t ws_size,
                              hipStream_t stream) {
  const float* hidden = (const float*)d_in[0];
  const float* mask   = (const float*)d_in[1];
  const float* wq = (const float*)d_in[2];
  const float* wk = (const float*)d_in[3];
  const float* wv = (const float*)d_in[4];
  const float* wo = (const float*)d_in[5];
  const float* nq = (const float*)d_in[6];
  const float* nk = (const float*)d_in[7];
  const float* nv = (const float*)d_in[8];
  const float* no = (const float*)d_in[9];
  float* out = (float*)d_out;
  char* ws = (char*)d_ws;

  constexpr size_t O_STATS = 0;
  constexpr size_t O_CT    = 256;
  constexpr size_t O_ST    = O_CT + 524288;
  constexpr size_t O_SQ    = O_ST + 524288;   // SQ|SK|SV|SO contiguous
  constexpr size_t O_SK    = O_SQ + 8388608;
  constexpr size_t O_SV    = O_SK + 4194304;
  constexpr size_t O_SO    = O_SV + 4194304;
  constexpr size_t O_RSQ   = O_SO + 8388608;
  constexpr size_t O_RSK   = O_RSQ + 16384;
  constexpr size_t O_RSV   = O_RSK + 16384;
  constexpr size_t O_RSO   = O_RSV + 16384;
  constexpr size_t O_AQQ   = O_RSO + 16384;
  constexpr size_t O_AQK   = O_AQQ + 16777216;
  constexpr size_t O_AQV   = O_AQK + 16777216;
  constexpr size_t O_QR    = O_AQV + 16777216;
  constexpr size_t O_KR    = O_QR + 16777216;
  constexpr size_t O_VT    = O_KR + 8388608;
  constexpr size_t O_VLIN2 = O_VT + 8388608;  // fp32 [4096,1024]
  constexpr size_t O_ATTN  = O_AQQ;           // alias: fp32 [4096,2048]
  constexpr size_t O_AQO   = O_AQV;           // alias

  float* stats = (float*)(ws + O_STATS);
  float* ct = (float*)(ws + O_CT);
  float* st = (float*)(ws + O_ST);

  (void)hipMemsetAsync(ws + O_STATS, 0, 256, stream);

  wstats_kernel<<<dim3(256, 4), 256, 0, stream>>>(wq, wk, wv, wo, stats);
  wsign_kernel<<<dim3(1024, 4), 256, 0, stream>>>(wq, wk, wv, wo,
      (ushort*)(ws + O_SQ), (ushort*)(ws + O_SK), (ushort*)(ws + O_SV), (ushort*)(ws + O_SO), stats);
  ropetab_kernel<<<dim3(2048), 64, 0, stream>>>(ct, st);

  rqnorm_kernel<3><<<dim3(4096), 256, 0, stream>>>(hidden, nq, nk, nv,
      (bf16*)(ws + O_AQQ), (bf16*)(ws + O_AQK), (bf16*)(ws + O_AQV),
      (float*)(ws + O_RSQ), (float*)(ws + O_RSK), (float*)(ws + O_RSV));

  qkv_gemm<<<dim3(32, 32), 256, 0, stream>>>(
      (const bf16*)(ws + O_AQQ), (const bf16*)(ws + O_AQK), (const bf16*)(ws + O_AQV),
      (const bf16*)(ws + O_SQ),
      (const float*)(ws + O_RSQ), (const float*)(ws + O_RSK), (const float*)(ws + O_RSV),
      stats, (bf16*)(ws + O_QR), (bf16*)(ws + O_KR), (float*)(ws + O_VLIN2), ct, st);

  vtrans_kernel<<<dim3(16, 64), 256, 0, stream>>>((const float*)(ws + O_VLIN2), (bf16*)(ws + O_VT));

  attn_kernel<<<dim3(16, 32), 256, 0, stream>>>(
      (const bf16*)(ws + O_QR), (const bf16*)(ws + O_KR), (const bf16*)(ws + O_VT),
      mask, (float*)(ws + O_ATTN));

  rqnorm_kernel<1><<<dim3(4096), 256, 0, stream>>>((const float*)(ws + O_ATTN), no, no, no,
      (bf16*)(ws + O_AQO), (bf16*)(ws + O_AQO), (bf16*)(ws + O_AQO),
      (float*)(ws + O_RSO), (float*)(ws + O_RSO), (float*)(ws + O_RSO));

  gemm_o<<<dim3(16, 32), 256, 0, stream>>>(
      (const bf16*)(ws + O_AQO), (const bf16*)(ws + O_SO), (float*)(ws + O_RSO), stats, out);

  (void)in_sizes; (void)n_in; (void)out_size; (void)ws_size;
}